// Round 1
// baseline (1911.677 us; speedup 1.0000x reference)
//
#include <hip/hip_runtime.h>
#include <stdint.h>

// Problem constants (fixed-shape problem)
#define N_NODES 50000
#define N_EDGES 200000
#define N_GRAPH 64
#define F_IN    1536
#define H_DIM   1024
#define C_OUT   80
#define FUSE_D  1024

typedef unsigned short u16;
typedef short s16x8 __attribute__((ext_vector_type(8)));
typedef float f32x4 __attribute__((ext_vector_type(4)));
typedef unsigned short u16x4 __attribute__((ext_vector_type(4)));

// ---------- bf16 helpers (bit-level, RNE) ----------
__device__ __forceinline__ float bf2f(u16 u) {
    union { unsigned int i; float f; } v; v.i = ((unsigned int)u) << 16; return v.f;
}
__device__ __forceinline__ u16 f2bf(float f) {
    union { float f; unsigned int i; } v; v.f = f;
    unsigned int x = v.i;
    unsigned int r = (x + 0x7fffu + ((x >> 16) & 1u)) >> 16;
    return (u16)r;
}

// async global->LDS, 16 bytes per lane (lds dest must be linear in lane order)
__device__ __forceinline__ void load_lds16(const void* g, void* l) {
    __builtin_amdgcn_global_load_lds(
        (const __attribute__((address_space(1))) void*)g,
        (__attribute__((address_space(3))) void*)l, 16, 0, 0);
}

// ---------- graph prep kernels ----------
__global__ void k_deg(const int* __restrict__ dst, int* cnt) {
    int e = blockIdx.x * blockDim.x + threadIdx.x;
    if (e < N_EDGES) atomicAdd(&cnt[dst[e]], 1);
}

__global__ void k_cg(const int* __restrict__ batch, int* cG) {
    int i = blockIdx.x * blockDim.x + threadIdx.x;
    if (i < N_NODES) atomicAdd(&cG[batch[i]], 1);
}

// single-block exclusive scan of cnt -> rowptr, plus dis = rsqrt(deg+1)
__global__ __launch_bounds__(1024) void k_scan(const int* __restrict__ cnt,
                                               int* __restrict__ rowptr,
                                               float* __restrict__ dis) {
    __shared__ int lds[1024];
    int t = threadIdx.x;
    const int CH = (N_NODES + 1023) / 1024;  // 49
    int beg = t * CH, end = min(beg + CH, N_NODES);
    int s = 0;
    for (int i = beg; i < end; ++i) s += cnt[i];
    lds[t] = s;
    __syncthreads();
    for (int off = 1; off < 1024; off <<= 1) {
        int v = (t >= off) ? lds[t - off] : 0;
        __syncthreads();
        lds[t] += v;
        __syncthreads();
    }
    int run = lds[t] - s;  // exclusive prefix
    for (int i = beg; i < end; ++i) {
        rowptr[i] = run;
        int c = cnt[i];
        run += c;
        dis[i] = rsqrtf((float)(c + 1));  // +1 self-loop; deg>=1 always
    }
    if (t == 1023) rowptr[N_NODES] = lds[1023];
}

__global__ void k_fill(const int* __restrict__ src, const int* __restrict__ dst,
                       const int* __restrict__ rowptr, int* cursor, int* col) {
    int e = blockIdx.x * blockDim.x + threadIdx.x;
    if (e < N_EDGES) {
        int d = dst[e];
        int p = atomicAdd(&cursor[d], 1);
        col[rowptr[d] + p] = src[e];
    }
}

// ---------- fp32 -> bf16 cast (vectorized) ----------
__global__ void k_cvt(const float* __restrict__ in, u16* __restrict__ out, long n) {
    long i = (long)blockIdx.x * blockDim.x + threadIdx.x;
    long stride = (long)gridDim.x * blockDim.x;
    for (long v = i * 4; v < n; v += stride * 4) {
        float4 f = *(const float4*)(in + v);
        u16x4 o = { f2bf(f.x), f2bf(f.y), f2bf(f.z), f2bf(f.w) };
        *(u16x4*)(out + v) = o;
    }
}

// W [K x Nn] fp32 -> Wt [Nn x K] bf16 (tiled transpose)
__global__ void k_trn(const float* __restrict__ W, u16* __restrict__ Wt, int K, int Nn) {
    __shared__ float tle[32][33];
    int n0 = blockIdx.x * 32, k0 = blockIdx.y * 32;
    int tx = threadIdx.x, ty = threadIdx.y;  // 32 x 8
    for (int i = ty; i < 32; i += 8)
        tle[i][tx] = W[(size_t)(k0 + i) * Nn + n0 + tx];
    __syncthreads();
    for (int i = ty; i < 32; i += 8)
        Wt[(size_t)(n0 + i) * K + k0 + tx] = f2bf(tle[tx][i]);
}

// ---------- MFMA GEMM: C[MxNn] = A[MxK] @ Bt[NnxK]^T, all bf16, C bf16 ----------
// 128x128 block tile, BK=32, 4 waves each 64x64 (4x4 of 16x16x32 MFMA).
__global__ __launch_bounds__(256) void gemm_bt(const u16* __restrict__ A,
                                               const u16* __restrict__ Bt,
                                               u16* __restrict__ C,
                                               int M, int Nn, int K) {
    __shared__ __attribute__((aligned(16))) u16 ldsA[128 * 32];
    __shared__ __attribute__((aligned(16))) u16 ldsB[128 * 32];
    int tid = threadIdx.x;
    int bM = blockIdx.x, bN = blockIdx.y;
    int lane = tid & 63, wave = tid >> 6;
    int wm = wave & 1, wn = wave >> 1;
    int qd = lane >> 4, lo = lane & 15;

    f32x4 acc[4][4] = {};

    // staging: 512 chunks of 16B per tile (2 per thread), linear in tid
    int idx0 = tid, idx1 = 256 + tid;
    int ar0 = bM * 128 + (idx0 >> 2); if (ar0 > M - 1) ar0 = M - 1;
    int ar1 = bM * 128 + (idx1 >> 2); if (ar1 > M - 1) ar1 = M - 1;
    const u16* Ab0 = A + (size_t)ar0 * K + (idx0 & 3) * 8;
    const u16* Ab1 = A + (size_t)ar1 * K + (idx1 & 3) * 8;
    const u16* Bb0 = Bt + (size_t)(bN * 128 + (idx0 >> 2)) * K + (idx0 & 3) * 8;
    const u16* Bb1 = Bt + (size_t)(bN * 128 + (idx1 >> 2)) * K + (idx1 & 3) * 8;

    for (int k0 = 0; k0 < K; k0 += 32) {
        __syncthreads();
        load_lds16(Ab0 + k0, &ldsA[idx0 * 8]);
        load_lds16(Ab1 + k0, &ldsA[idx1 * 8]);
        load_lds16(Bb0 + k0, &ldsB[idx0 * 8]);
        load_lds16(Bb1 + k0, &ldsB[idx1 * 8]);
        __syncthreads();

        s16x8 af[4], bfr[4];
#pragma unroll
        for (int r = 0; r < 4; r++)
            af[r] = *(const s16x8*)&ldsA[(wm * 64 + r * 16 + lo) * 32 + qd * 8];
#pragma unroll
        for (int c = 0; c < 4; c++)
            bfr[c] = *(const s16x8*)&ldsB[(wn * 64 + c * 16 + lo) * 32 + qd * 8];
#pragma unroll
        for (int r = 0; r < 4; r++)
#pragma unroll
            for (int c = 0; c < 4; c++)
                acc[r][c] = __builtin_amdgcn_mfma_f32_16x16x32_bf16(af[r], bfr[c], acc[r][c], 0, 0, 0);
    }

    // C/D layout: col = lane&15, row = quad*4 + reg  [verified m89/m91]
#pragma unroll
    for (int r = 0; r < 4; r++) {
        int row0 = bM * 128 + wm * 64 + r * 16 + qd * 4;
#pragma unroll
        for (int c = 0; c < 4; c++) {
            int colI = bN * 128 + wn * 64 + c * 16 + lo;
            f32x4 a = acc[r][c];
#pragma unroll
            for (int reg = 0; reg < 4; reg++) {
                int row = row0 + reg;
                if (row < M) C[(size_t)row * Nn + colI] = f2bf(a[reg]);
            }
        }
    }
}

// ---------- GCN aggregation: out[i] = relu(dis_i^2*h[i] + sum_e dis_i*dis_src*h[src] + b) ----------
__global__ __launch_bounds__(256) void k_agg(const u16* __restrict__ hin, u16* __restrict__ hout,
                                             const int* __restrict__ rowptr, const int* __restrict__ col,
                                             const float* __restrict__ dis, const float* __restrict__ bias) {
    int i = blockIdx.x;
    int t = threadIdx.x;  // 256 threads x 4 features
    float di = dis[i];
    int beg = rowptr[i], end = rowptr[i + 1];
    u16x4 v = *(const u16x4*)&hin[(size_t)i * H_DIM + t * 4];
    float w0 = di * di;
    float a0 = w0 * bf2f(v[0]), a1 = w0 * bf2f(v[1]);
    float a2 = w0 * bf2f(v[2]), a3 = w0 * bf2f(v[3]);
    for (int e = beg; e < end; ++e) {
        int s = col[e];                     // block-uniform
        float w = di * dis[s];
        u16x4 u = *(const u16x4*)&hin[(size_t)s * H_DIM + t * 4];
        a0 += w * bf2f(u[0]); a1 += w * bf2f(u[1]);
        a2 += w * bf2f(u[2]); a3 += w * bf2f(u[3]);
    }
    const float4 b = *(const float4*)&bias[t * 4];
    a0 = fmaxf(a0 + b.x, 0.f); a1 = fmaxf(a1 + b.y, 0.f);
    a2 = fmaxf(a2 + b.z, 0.f); a3 = fmaxf(a3 + b.w, 0.f);
    u16x4 o = { f2bf(a0), f2bf(a1), f2bf(a2), f2bf(a3) };
    *(u16x4*)&hout[(size_t)i * H_DIM + t * 4] = o;
}

// ---------- mean pool over sorted batch segments ----------
__global__ __launch_bounds__(256) void k_pool(const u16* __restrict__ h, const int* __restrict__ cG,
                                              float* __restrict__ pooled) {
    int g = blockIdx.x, fc = blockIdx.y, t = threadIdx.x;
    int f = fc * 256 + t;
    int start = 0;
    for (int j = 0; j < g; ++j) start += cG[j];  // uniform, cached
    int cntg = cG[g];
    float acc = 0.f;
    for (int n = start; n < start + cntg; ++n)
        acc += bf2f(h[(size_t)n * H_DIM + f]);
    pooled[g * H_DIM + f] = acc / (float)max(cntg, 1);
}

// ---------- MLP head (fp32) ----------
// block: (gq in 0..15 -> 4 graphs, jq in 0..3 -> 256 outputs), 256 threads
__global__ __launch_bounds__(256) void k_mlp1(const float* __restrict__ gx, const float* __restrict__ pooled,
                                              const float* __restrict__ fw1, const float* __restrict__ fb1,
                                              float* __restrict__ hid) {
    __shared__ float comb[4 * (F_IN + H_DIM)];
    const int KD = F_IN + H_DIM;  // 2560
    int gq = blockIdx.x, jq = blockIdx.y, t = threadIdx.x;
    for (int idx = t; idx < 4 * KD; idx += 256) {
        int gl = idx / KD, k = idx % KD;
        int g = gq * 4 + gl;
        comb[idx] = (k < F_IN) ? gx[g * F_IN + k] : pooled[g * H_DIM + (k - F_IN)];
    }
    __syncthreads();
    int j = jq * 256 + t;
    float a0 = 0, a1 = 0, a2 = 0, a3 = 0;
    for (int k = 0; k < KD; ++k) {
        float w = fw1[(size_t)k * FUSE_D + j];  // coalesced across lanes
        a0 += comb[k] * w;
        a1 += comb[KD + k] * w;
        a2 += comb[2 * KD + k] * w;
        a3 += comb[3 * KD + k] * w;
    }
    float b = fb1[j];
    hid[(size_t)(gq * 4 + 0) * FUSE_D + j] = fmaxf(a0 + b, 0.f);
    hid[(size_t)(gq * 4 + 1) * FUSE_D + j] = fmaxf(a1 + b, 0.f);
    hid[(size_t)(gq * 4 + 2) * FUSE_D + j] = fmaxf(a2 + b, 0.f);
    hid[(size_t)(gq * 4 + 3) * FUSE_D + j] = fmaxf(a3 + b, 0.f);
}

__global__ __launch_bounds__(128) void k_mlp2(const float* __restrict__ hid, const float* __restrict__ fw2,
                                              const float* __restrict__ fb2, float* __restrict__ out) {
    __shared__ float hh[FUSE_D];
    int g = blockIdx.x, t = threadIdx.x;
    for (int idx = t; idx < FUSE_D; idx += 128) hh[idx] = hid[(size_t)g * FUSE_D + idx];
    __syncthreads();
    if (t < C_OUT) {
        float acc = fb2[t];
        for (int k = 0; k < FUSE_D; ++k) acc += hh[k] * fw2[k * C_OUT + t];
        out[g * C_OUT + t] = acc;
    }
}

extern "C" void kernel_launch(void* const* d_in, const int* in_sizes, int n_in,
                              void* d_out, int out_size, void* d_ws, size_t ws_size,
                              hipStream_t stream) {
    (void)in_sizes; (void)n_in; (void)out_size;
    const float* gx    = (const float*)d_in[0];
    const float* x     = (const float*)d_in[1];
    const int*   ei    = (const int*)d_in[2];
    const int*   batch = (const int*)d_in[3];
    const float* W1    = (const float*)d_in[4];
    const float* b1    = (const float*)d_in[5];
    const float* W2    = (const float*)d_in[6];
    const float* b2    = (const float*)d_in[7];
    const float* fw1   = (const float*)d_in[8];
    const float* fb1   = (const float*)d_in[9];
    const float* fw2   = (const float*)d_in[10];
    const float* fb2   = (const float*)d_in[11];
    float* out = (float*)d_out;
    const int* src = ei;
    const int* dst = ei + N_EDGES;

    // workspace layout (~366 MB total)
    char* ws = (char*)d_ws;
    size_t off = 0;
    auto alloc = [&](size_t bytes) -> char* {
        char* p = ws + off;
        off += (bytes + 255) & ~(size_t)255;
        return p;
    };
    u16*  xb     = (u16*)alloc((size_t)N_NODES * F_IN * 2);   // reused as h2b
    u16*  h0b    = (u16*)alloc((size_t)N_NODES * H_DIM * 2);  // reused as h3b
    u16*  h1b    = (u16*)alloc((size_t)N_NODES * H_DIM * 2);
    u16*  W1T    = (u16*)alloc((size_t)H_DIM * F_IN * 2);
    u16*  W2T    = (u16*)alloc((size_t)H_DIM * H_DIM * 2);
    float* pooled = (float*)alloc((size_t)N_GRAPH * H_DIM * 4);
    float* hid    = (float*)alloc((size_t)N_GRAPH * FUSE_D * 4);
    float* dis    = (float*)alloc((size_t)N_NODES * 4);
    int* rowptr   = (int*)alloc((size_t)(N_NODES + 1) * 4);
    int* col      = (int*)alloc((size_t)N_EDGES * 4);
    int* cnt      = (int*)alloc((size_t)N_NODES * 4);   // zero zone start
    int* cursor   = (int*)alloc((size_t)N_NODES * 4);
    int* cG       = (int*)alloc(256);
    u16* h2b = xb;
    u16* h3b = h0b;
    (void)ws_size;

    // zero the accumulation zone (ws is poisoned 0xAA before every call)
    size_t zbytes = (size_t)((char*)cG - (char*)cnt) + 256;
    hipMemsetAsync(cnt, 0, zbytes, stream);

    // graph prep
    k_deg<<<(N_EDGES + 255) / 256, 256, 0, stream>>>(dst, cnt);
    k_cg<<<(N_NODES + 255) / 256, 256, 0, stream>>>(batch, cG);
    k_scan<<<1, 1024, 0, stream>>>(cnt, rowptr, dis);
    k_fill<<<(N_EDGES + 255) / 256, 256, 0, stream>>>(src, dst, rowptr, cursor, col);

    // casts / weight transposes
    k_cvt<<<4096, 256, 0, stream>>>(x, xb, (long)N_NODES * F_IN);
    k_trn<<<dim3(H_DIM / 32, F_IN / 32), dim3(32, 8), 0, stream>>>(W1, W1T, F_IN, H_DIM);
    k_trn<<<dim3(H_DIM / 32, H_DIM / 32), dim3(32, 8), 0, stream>>>(W2, W2T, H_DIM, H_DIM);

    // layer 1
    gemm_bt<<<dim3((N_NODES + 127) / 128, H_DIM / 128), 256, 0, stream>>>(xb, W1T, h0b, N_NODES, H_DIM, F_IN);
    k_agg<<<N_NODES, 256, 0, stream>>>(h0b, h1b, rowptr, col, dis, b1);
    // layer 2
    gemm_bt<<<dim3((N_NODES + 127) / 128, H_DIM / 128), 256, 0, stream>>>(h1b, W2T, h2b, N_NODES, H_DIM, H_DIM);
    k_agg<<<N_NODES, 256, 0, stream>>>(h2b, h3b, rowptr, col, dis, b2);

    // pool + head
    k_pool<<<dim3(N_GRAPH, H_DIM / 256), 256, 0, stream>>>(h3b, cG, pooled);
    k_mlp1<<<dim3(N_GRAPH / 4, FUSE_D / 256), 256, 0, stream>>>(gx, pooled, fw1, fb1, hid);
    k_mlp2<<<N_GRAPH, 128, 0, stream>>>(hid, fw2, fb2, out);
}

// Round 2
// 1653.018 us; speedup vs baseline: 1.1565x; 1.1565x over previous
//
#include <hip/hip_runtime.h>
#include <stdint.h>

// Problem constants (fixed-shape problem)
#define N_NODES 50000
#define N_EDGES 200000
#define N_GRAPH 64
#define F_IN    1536
#define H_DIM   1024
#define C_OUT   80
#define FUSE_D  1024
#define POOL_CHUNK 128
#define MLP1_KC 320   // 2560 / 8 k-chunks

typedef unsigned short u16;
typedef short s16x8 __attribute__((ext_vector_type(8)));
typedef float f32x4 __attribute__((ext_vector_type(4)));
typedef unsigned short u16x4 __attribute__((ext_vector_type(4)));

// ---------- bf16 helpers (bit-level, RNE) ----------
__device__ __forceinline__ float bf2f(u16 u) {
    union { unsigned int i; float f; } v; v.i = ((unsigned int)u) << 16; return v.f;
}
__device__ __forceinline__ u16 f2bf(float f) {
    union { float f; unsigned int i; } v; v.f = f;
    unsigned int x = v.i;
    unsigned int r = (x + 0x7fffu + ((x >> 16) & 1u)) >> 16;
    return (u16)r;
}

// async global->LDS, 16 bytes per lane (lds dest must be linear in lane order)
__device__ __forceinline__ void load_lds16(const void* g, void* l) {
    __builtin_amdgcn_global_load_lds(
        (const __attribute__((address_space(1))) void*)g,
        (__attribute__((address_space(3))) void*)l, 16, 0, 0);
}

// ---------- graph prep kernels ----------
__global__ void k_deg(const int* __restrict__ dst, int* cnt) {
    int e = blockIdx.x * blockDim.x + threadIdx.x;
    if (e < N_EDGES) atomicAdd(&cnt[dst[e]], 1);
}

__global__ void k_cg(const int* __restrict__ batch, int* cG) {
    int i = blockIdx.x * blockDim.x + threadIdx.x;
    if (i < N_NODES) atomicAdd(&cG[batch[i]], 1);
}

// single-block exclusive scan of cnt -> rowptr, plus dis = rsqrt(deg+1)
__global__ __launch_bounds__(1024) void k_scan(const int* __restrict__ cnt,
                                               int* __restrict__ rowptr,
                                               float* __restrict__ dis) {
    __shared__ int lds[1024];
    int t = threadIdx.x;
    const int CH = (N_NODES + 1023) / 1024;  // 49
    int beg = t * CH, end = min(beg + CH, N_NODES);
    int s = 0;
    for (int i = beg; i < end; ++i) s += cnt[i];
    lds[t] = s;
    __syncthreads();
    for (int off = 1; off < 1024; off <<= 1) {
        int v = (t >= off) ? lds[t - off] : 0;
        __syncthreads();
        lds[t] += v;
        __syncthreads();
    }
    int run = lds[t] - s;  // exclusive prefix
    for (int i = beg; i < end; ++i) {
        rowptr[i] = run;
        int c = cnt[i];
        run += c;
        dis[i] = rsqrtf((float)(c + 1));  // +1 self-loop; deg>=1 always
    }
    if (t == 1023) rowptr[N_NODES] = lds[1023];
}

__global__ void k_fill(const int* __restrict__ src, const int* __restrict__ dst,
                       const int* __restrict__ rowptr, int* cursor, int* col) {
    int e = blockIdx.x * blockDim.x + threadIdx.x;
    if (e < N_EDGES) {
        int d = dst[e];
        int p = atomicAdd(&cursor[d], 1);
        col[rowptr[d] + p] = src[e];
    }
}

// ---------- fp32 -> bf16 cast (vectorized) ----------
__global__ void k_cvt(const float* __restrict__ in, u16* __restrict__ out, long n) {
    long i = (long)blockIdx.x * blockDim.x + threadIdx.x;
    long stride = (long)gridDim.x * blockDim.x;
    for (long v = i * 4; v < n; v += stride * 4) {
        float4 f = *(const float4*)(in + v);
        u16x4 o = { f2bf(f.x), f2bf(f.y), f2bf(f.z), f2bf(f.w) };
        *(u16x4*)(out + v) = o;
    }
}

// W [K x Nn] fp32 -> Wt [Nn x K] bf16 (tiled transpose)
__global__ void k_trn(const float* __restrict__ W, u16* __restrict__ Wt, int K, int Nn) {
    __shared__ float tle[32][33];
    int n0 = blockIdx.x * 32, k0 = blockIdx.y * 32;
    int tx = threadIdx.x, ty = threadIdx.y;  // 32 x 8
    for (int i = ty; i < 32; i += 8)
        tle[i][tx] = W[(size_t)(k0 + i) * Nn + n0 + tx];
    __syncthreads();
    for (int i = ty; i < 32; i += 8)
        Wt[(size_t)(n0 + i) * K + k0 + tx] = f2bf(tle[tx][i]);
}

// ---------- MFMA GEMM: C[MxNn] = A[MxK] @ Bt[NnxK]^T, all bf16, C bf16 ----------
// 128x128 block tile, BK=32, 4 waves each 64x64 (4x4 of 16x16x32 MFMA).
// Grid: (N-tiles, M-tiles) — N fastest so consecutive blocks share the A-tile (L2 reuse).
__global__ __launch_bounds__(256) void gemm_bt(const u16* __restrict__ A,
                                               const u16* __restrict__ Bt,
                                               u16* __restrict__ C,
                                               int M, int Nn, int K) {
    __shared__ __attribute__((aligned(16))) u16 ldsA[128 * 32];
    __shared__ __attribute__((aligned(16))) u16 ldsB[128 * 32];
    int tid = threadIdx.x;
    int bN = blockIdx.x, bM = blockIdx.y;
    int lane = tid & 63, wave = tid >> 6;
    int wm = wave & 1, wn = wave >> 1;
    int qd = lane >> 4, lo = lane & 15;

    f32x4 acc[4][4] = {};

    // staging: 512 chunks of 16B per tile (2 per thread), linear in tid
    int idx0 = tid, idx1 = 256 + tid;
    int ar0 = bM * 128 + (idx0 >> 2); if (ar0 > M - 1) ar0 = M - 1;
    int ar1 = bM * 128 + (idx1 >> 2); if (ar1 > M - 1) ar1 = M - 1;
    const u16* Ab0 = A + (size_t)ar0 * K + (idx0 & 3) * 8;
    const u16* Ab1 = A + (size_t)ar1 * K + (idx1 & 3) * 8;
    const u16* Bb0 = Bt + (size_t)(bN * 128 + (idx0 >> 2)) * K + (idx0 & 3) * 8;
    const u16* Bb1 = Bt + (size_t)(bN * 128 + (idx1 >> 2)) * K + (idx1 & 3) * 8;

    for (int k0 = 0; k0 < K; k0 += 32) {
        __syncthreads();
        load_lds16(Ab0 + k0, &ldsA[idx0 * 8]);
        load_lds16(Ab1 + k0, &ldsA[idx1 * 8]);
        load_lds16(Bb0 + k0, &ldsB[idx0 * 8]);
        load_lds16(Bb1 + k0, &ldsB[idx1 * 8]);
        __syncthreads();

        s16x8 af[4], bfr[4];
#pragma unroll
        for (int r = 0; r < 4; r++)
            af[r] = *(const s16x8*)&ldsA[(wm * 64 + r * 16 + lo) * 32 + qd * 8];
#pragma unroll
        for (int c = 0; c < 4; c++)
            bfr[c] = *(const s16x8*)&ldsB[(wn * 64 + c * 16 + lo) * 32 + qd * 8];
#pragma unroll
        for (int r = 0; r < 4; r++)
#pragma unroll
            for (int c = 0; c < 4; c++)
                acc[r][c] = __builtin_amdgcn_mfma_f32_16x16x32_bf16(af[r], bfr[c], acc[r][c], 0, 0, 0);
    }

    // C/D layout: col = lane&15, row = quad*4 + reg  [verified m89/m91]
#pragma unroll
    for (int r = 0; r < 4; r++) {
        int row0 = bM * 128 + wm * 64 + r * 16 + qd * 4;
#pragma unroll
        for (int c = 0; c < 4; c++) {
            int colI = bN * 128 + wn * 64 + c * 16 + lo;
            f32x4 a = acc[r][c];
#pragma unroll
            for (int reg = 0; reg < 4; reg++) {
                int row = row0 + reg;
                if (row < M) C[(size_t)row * Nn + colI] = f2bf(a[reg]);
            }
        }
    }
}

// ---------- GCN aggregation: out[i] = relu(dis_i^2*h[i] + sum_e dis_i*dis_src*h[src] + b) ----------
__global__ __launch_bounds__(256) void k_agg(const u16* __restrict__ hin, u16* __restrict__ hout,
                                             const int* __restrict__ rowptr, const int* __restrict__ col,
                                             const float* __restrict__ dis, const float* __restrict__ bias) {
    int i = blockIdx.x;
    int t = threadIdx.x;  // 256 threads x 4 features
    float di = dis[i];
    int beg = rowptr[i], end = rowptr[i + 1];
    u16x4 v = *(const u16x4*)&hin[(size_t)i * H_DIM + t * 4];
    float w0 = di * di;
    float a0 = w0 * bf2f(v[0]), a1 = w0 * bf2f(v[1]);
    float a2 = w0 * bf2f(v[2]), a3 = w0 * bf2f(v[3]);
    for (int e = beg; e < end; ++e) {
        int s = col[e];                     // block-uniform
        float w = di * dis[s];
        u16x4 u = *(const u16x4*)&hin[(size_t)s * H_DIM + t * 4];
        a0 += w * bf2f(u[0]); a1 += w * bf2f(u[1]);
        a2 += w * bf2f(u[2]); a3 += w * bf2f(u[3]);
    }
    const float4 b = *(const float4*)&bias[t * 4];
    a0 = fmaxf(a0 + b.x, 0.f); a1 = fmaxf(a1 + b.y, 0.f);
    a2 = fmaxf(a2 + b.z, 0.f); a3 = fmaxf(a3 + b.w, 0.f);
    u16x4 o = { f2bf(a0), f2bf(a1), f2bf(a2), f2bf(a3) };
    *(u16x4*)&hout[(size_t)i * H_DIM + t * 4] = o;
}

// ---------- mean pool: chunked nodes, register segment-accumulate, atomic flush ----------
// grid: ceil(N/POOL_CHUNK) blocks x 256 threads (4 features each). batch sorted.
__global__ __launch_bounds__(256) void k_pool(const u16* __restrict__ h, const int* __restrict__ batch,
                                              float* __restrict__ pooled) {
    int t = threadIdx.x;
    int n0 = blockIdx.x * POOL_CHUNK;
    int n1 = min(n0 + POOL_CHUNK, N_NODES);
    float a0 = 0.f, a1 = 0.f, a2 = 0.f, a3 = 0.f;
    int curg = batch[n0];
    for (int n = n0; n < n1; ++n) {
        int g = batch[n];  // block-uniform
        if (g != curg) {   // uniform branch (rare: ~1-2 per block)
            float* p = &pooled[(size_t)curg * H_DIM + t * 4];
            atomicAdd(p + 0, a0); atomicAdd(p + 1, a1);
            atomicAdd(p + 2, a2); atomicAdd(p + 3, a3);
            a0 = a1 = a2 = a3 = 0.f;
            curg = g;
        }
        u16x4 v = *(const u16x4*)&h[(size_t)n * H_DIM + t * 4];
        a0 += bf2f(v[0]); a1 += bf2f(v[1]); a2 += bf2f(v[2]); a3 += bf2f(v[3]);
    }
    float* p = &pooled[(size_t)curg * H_DIM + t * 4];
    atomicAdd(p + 0, a0); atomicAdd(p + 1, a1);
    atomicAdd(p + 2, a2); atomicAdd(p + 3, a3);
}

// ---------- MLP head layer 1, split-K with atomic accumulation ----------
// grid: (16 gq, 4 jq, 8 kq); block 256. comb = [gx | pooled/count] per 4 graphs.
// hid accumulates raw (pre-bias, pre-relu); MLP2 applies bias+relu.
__global__ __launch_bounds__(256) void k_mlp1(const float* __restrict__ gx, const float* __restrict__ pooled,
                                              const int* __restrict__ cG,
                                              const float* __restrict__ fw1, float* __restrict__ hid) {
    __shared__ float comb[4 * MLP1_KC];
    const int KD = F_IN + H_DIM;  // 2560
    int gq = blockIdx.x, jq = blockIdx.y, kq = blockIdx.z, t = threadIdx.x;
    int kbeg = kq * MLP1_KC;
    for (int idx = t; idx < 4 * MLP1_KC; idx += 256) {
        int gl = idx / MLP1_KC, kk = idx % MLP1_KC;
        int k = kbeg + kk;
        int g = gq * 4 + gl;
        float v;
        if (k < F_IN) v = gx[(size_t)g * F_IN + k];
        else v = pooled[(size_t)g * H_DIM + (k - F_IN)] / (float)max(cG[g], 1);
        comb[idx] = v;
    }
    __syncthreads();
    int j = jq * 256 + t;
    float a0 = 0, a1 = 0, a2 = 0, a3 = 0;
    for (int kk = 0; kk < MLP1_KC; ++kk) {
        float w = fw1[(size_t)(kbeg + kk) * FUSE_D + j];  // coalesced across lanes
        a0 += comb[kk] * w;
        a1 += comb[MLP1_KC + kk] * w;
        a2 += comb[2 * MLP1_KC + kk] * w;
        a3 += comb[3 * MLP1_KC + kk] * w;
    }
    atomicAdd(&hid[(size_t)(gq * 4 + 0) * FUSE_D + j], a0);
    atomicAdd(&hid[(size_t)(gq * 4 + 1) * FUSE_D + j], a1);
    atomicAdd(&hid[(size_t)(gq * 4 + 2) * FUSE_D + j], a2);
    atomicAdd(&hid[(size_t)(gq * 4 + 3) * FUSE_D + j], a3);
}

__global__ __launch_bounds__(128) void k_mlp2(const float* __restrict__ hid, const float* __restrict__ fb1,
                                              const float* __restrict__ fw2,
                                              const float* __restrict__ fb2, float* __restrict__ out) {
    __shared__ float hh[FUSE_D];
    int g = blockIdx.x, t = threadIdx.x;
    for (int idx = t; idx < FUSE_D; idx += 128)
        hh[idx] = fmaxf(hid[(size_t)g * FUSE_D + idx] + fb1[idx], 0.f);  // fused bias+relu
    __syncthreads();
    if (t < C_OUT) {
        float acc = fb2[t];
        for (int k = 0; k < FUSE_D; ++k) acc += hh[k] * fw2[k * C_OUT + t];
        out[g * C_OUT + t] = acc;
    }
}

extern "C" void kernel_launch(void* const* d_in, const int* in_sizes, int n_in,
                              void* d_out, int out_size, void* d_ws, size_t ws_size,
                              hipStream_t stream) {
    (void)in_sizes; (void)n_in; (void)out_size;
    const float* gx    = (const float*)d_in[0];
    const float* x     = (const float*)d_in[1];
    const int*   ei    = (const int*)d_in[2];
    const int*   batch = (const int*)d_in[3];
    const float* W1    = (const float*)d_in[4];
    const float* b1    = (const float*)d_in[5];
    const float* W2    = (const float*)d_in[6];
    const float* b2    = (const float*)d_in[7];
    const float* fw1   = (const float*)d_in[8];
    const float* fb1   = (const float*)d_in[9];
    const float* fw2   = (const float*)d_in[10];
    const float* fb2   = (const float*)d_in[11];
    float* out = (float*)d_out;
    const int* src = ei;
    const int* dst = ei + N_EDGES;

    // workspace layout (~366 MB total); zero zone at the end
    char* ws = (char*)d_ws;
    size_t off = 0;
    auto alloc = [&](size_t bytes) -> char* {
        char* p = ws + off;
        off += (bytes + 255) & ~(size_t)255;
        return p;
    };
    u16*  xb     = (u16*)alloc((size_t)N_NODES * F_IN * 2);   // reused as h2b
    u16*  h0b    = (u16*)alloc((size_t)N_NODES * H_DIM * 2);  // reused as h3b
    u16*  h1b    = (u16*)alloc((size_t)N_NODES * H_DIM * 2);
    u16*  W1T    = (u16*)alloc((size_t)H_DIM * F_IN * 2);
    u16*  W2T    = (u16*)alloc((size_t)H_DIM * H_DIM * 2);
    float* dis    = (float*)alloc((size_t)N_NODES * 4);
    int* rowptr   = (int*)alloc((size_t)(N_NODES + 1) * 4);
    int* col      = (int*)alloc((size_t)N_EDGES * 4);
    // ---- zero zone start ----
    int* cnt      = (int*)alloc((size_t)N_NODES * 4);
    int* cursor   = (int*)alloc((size_t)N_NODES * 4);
    int* cG       = (int*)alloc(256);
    float* pooled = (float*)alloc((size_t)N_GRAPH * H_DIM * 4);
    float* hid    = (float*)alloc((size_t)N_GRAPH * FUSE_D * 4);
    u16* h2b = xb;
    u16* h3b = h0b;
    (void)ws_size;

    // zero the accumulation zone (ws is poisoned 0xAA before every call)
    size_t zbytes = (size_t)((char*)(hid + N_GRAPH * FUSE_D) - (char*)cnt);
    hipMemsetAsync(cnt, 0, zbytes, stream);

    // graph prep
    k_deg<<<(N_EDGES + 255) / 256, 256, 0, stream>>>(dst, cnt);
    k_cg<<<(N_NODES + 255) / 256, 256, 0, stream>>>(batch, cG);
    k_scan<<<1, 1024, 0, stream>>>(cnt, rowptr, dis);
    k_fill<<<(N_EDGES + 255) / 256, 256, 0, stream>>>(src, dst, rowptr, cursor, col);

    // casts / weight transposes
    k_cvt<<<4096, 256, 0, stream>>>(x, xb, (long)N_NODES * F_IN);
    k_trn<<<dim3(H_DIM / 32, F_IN / 32), dim3(32, 8), 0, stream>>>(W1, W1T, F_IN, H_DIM);
    k_trn<<<dim3(H_DIM / 32, H_DIM / 32), dim3(32, 8), 0, stream>>>(W2, W2T, H_DIM, H_DIM);

    // layer 1 (grid: N-tiles fastest for A-tile L2 reuse)
    gemm_bt<<<dim3(H_DIM / 128, (N_NODES + 127) / 128), 256, 0, stream>>>(xb, W1T, h0b, N_NODES, H_DIM, F_IN);
    k_agg<<<N_NODES, 256, 0, stream>>>(h0b, h1b, rowptr, col, dis, b1);
    // layer 2
    gemm_bt<<<dim3(H_DIM / 128, (N_NODES + 127) / 128), 256, 0, stream>>>(h1b, W2T, h2b, N_NODES, H_DIM, H_DIM);
    k_agg<<<N_NODES, 256, 0, stream>>>(h2b, h3b, rowptr, col, dis, b2);

    // pool + head
    k_pool<<<(N_NODES + POOL_CHUNK - 1) / POOL_CHUNK, 256, 0, stream>>>(h3b, batch, pooled);
    k_mlp1<<<dim3(N_GRAPH / 4, FUSE_D / 256, 8), 256, 0, stream>>>(gx, pooled, cG, fw1, hid);
    k_mlp2<<<N_GRAPH, 128, 0, stream>>>(hid, fb1, fw2, fb2, out);
}

// Round 3
// 1623.636 us; speedup vs baseline: 1.1774x; 1.0181x over previous
//
#include <hip/hip_runtime.h>
#include <stdint.h>

// Problem constants (fixed-shape problem)
#define N_NODES 50000
#define N_EDGES 200000
#define N_GRAPH 64
#define F_IN    1536
#define H_DIM   1024
#define C_OUT   80
#define FUSE_D  1024
#define POOL_CHUNK 128
#define MLP1_KC 320   // 2560 / 8 k-chunks

typedef unsigned short u16;
typedef short s16x8 __attribute__((ext_vector_type(8)));
typedef float f32x4 __attribute__((ext_vector_type(4)));
typedef unsigned short u16x4 __attribute__((ext_vector_type(4)));

// ---------- bf16 helpers (bit-level, RNE) ----------
__device__ __forceinline__ float bf2f(u16 u) {
    union { unsigned int i; float f; } v; v.i = ((unsigned int)u) << 16; return v.f;
}
__device__ __forceinline__ u16 f2bf(float f) {
    union { float f; unsigned int i; } v; v.f = f;
    unsigned int x = v.i;
    unsigned int r = (x + 0x7fffu + ((x >> 16) & 1u)) >> 16;
    return (u16)r;
}

// async global->LDS, 16 bytes per lane (lds dest must be linear in lane order)
__device__ __forceinline__ void load_lds16(const void* g, void* l) {
    __builtin_amdgcn_global_load_lds(
        (const __attribute__((address_space(1))) void*)g,
        (__attribute__((address_space(3))) void*)l, 16, 0, 0);
}

// ---------- graph prep kernels ----------
__global__ void k_deg(const int* __restrict__ dst, int* cnt) {
    int e = blockIdx.x * blockDim.x + threadIdx.x;
    if (e < N_EDGES) atomicAdd(&cnt[dst[e]], 1);
}

__global__ void k_cg(const int* __restrict__ batch, int* cG) {
    int i = blockIdx.x * blockDim.x + threadIdx.x;
    if (i < N_NODES) atomicAdd(&cG[batch[i]], 1);
}

// single-block exclusive scan of cnt -> rowptr, plus dis = rsqrt(deg+1)
__global__ __launch_bounds__(1024) void k_scan(const int* __restrict__ cnt,
                                               int* __restrict__ rowptr,
                                               float* __restrict__ dis) {
    __shared__ int lds[1024];
    int t = threadIdx.x;
    const int CH = (N_NODES + 1023) / 1024;  // 49
    int beg = t * CH, end = min(beg + CH, N_NODES);
    int s = 0;
    for (int i = beg; i < end; ++i) s += cnt[i];
    lds[t] = s;
    __syncthreads();
    for (int off = 1; off < 1024; off <<= 1) {
        int v = (t >= off) ? lds[t - off] : 0;
        __syncthreads();
        lds[t] += v;
        __syncthreads();
    }
    int run = lds[t] - s;  // exclusive prefix
    for (int i = beg; i < end; ++i) {
        rowptr[i] = run;
        int c = cnt[i];
        run += c;
        dis[i] = rsqrtf((float)(c + 1));  // +1 self-loop; deg>=1 always
    }
    if (t == 1023) rowptr[N_NODES] = lds[1023];
}

__global__ void k_fill(const int* __restrict__ src, const int* __restrict__ dst,
                       const int* __restrict__ rowptr, int* cursor, int* col) {
    int e = blockIdx.x * blockDim.x + threadIdx.x;
    if (e < N_EDGES) {
        int d = dst[e];
        int p = atomicAdd(&cursor[d], 1);
        col[rowptr[d] + p] = src[e];
    }
}

// ---------- fp32 -> bf16 cast (vectorized) ----------
__global__ void k_cvt(const float* __restrict__ in, u16* __restrict__ out, long n) {
    long i = (long)blockIdx.x * blockDim.x + threadIdx.x;
    long stride = (long)gridDim.x * blockDim.x;
    for (long v = i * 4; v < n; v += stride * 4) {
        float4 f = *(const float4*)(in + v);
        u16x4 o = { f2bf(f.x), f2bf(f.y), f2bf(f.z), f2bf(f.w) };
        *(u16x4*)(out + v) = o;
    }
}

// W [K x Nn] fp32 -> Wt [Nn x K] bf16 (tiled transpose)
__global__ void k_trn(const float* __restrict__ W, u16* __restrict__ Wt, int K, int Nn) {
    __shared__ float tle[32][33];
    int n0 = blockIdx.x * 32, k0 = blockIdx.y * 32;
    int tx = threadIdx.x, ty = threadIdx.y;  // 32 x 8
    for (int i = ty; i < 32; i += 8)
        tle[i][tx] = W[(size_t)(k0 + i) * Nn + n0 + tx];
    __syncthreads();
    for (int i = ty; i < 32; i += 8)
        Wt[(size_t)(n0 + i) * K + k0 + tx] = f2bf(tle[tx][i]);
}

// ---------- MFMA GEMM: C[MxNn] = A[MxK] @ Bt[NnxK]^T, all bf16, C bf16 ----------
// 128x128 block tile, BK=32, 4 waves each 64x64 (4x4 of 16x16x32 MFMA).
// XCD-aware swizzle: HW dispatches blocks round-robin over 8 XCDs (xcd = l%8).
// We map all 8 N-tiles of one M-tile group to the SAME xcd so the A-tile is
// fetched into exactly one XCD L2. Requires Nn == 1024 (8 N-tiles).
// Grid: 1-D, 8 * MTpad blocks, MTpad = ceil(MT/8)*8.
__global__ __launch_bounds__(256) void gemm_bt(const u16* __restrict__ A,
                                               const u16* __restrict__ Bt,
                                               u16* __restrict__ C,
                                               int M, int Nn, int K) {
    __shared__ __attribute__((aligned(16))) u16 ldsA[128 * 32];
    __shared__ __attribute__((aligned(16))) u16 ldsB[128 * 32];
    int l = blockIdx.x;
    int r = l & 7;             // XCD id (assumed round-robin l%8)
    int o = l >> 3;            // per-XCD ordinal
    int bN = o & 7;            // 8 N-tiles (Nn=1024)
    int bM = r + ((o >> 3) << 3);
    int MT = (M + 127) >> 7;
    if (bM >= MT) return;

    int tid = threadIdx.x;
    int lane = tid & 63, wave = tid >> 6;
    int wm = wave & 1, wn = wave >> 1;
    int qd = lane >> 4, lo = lane & 15;

    f32x4 acc[4][4] = {};

    // staging: 512 chunks of 16B per tile (2 per thread), linear in tid
    int idx0 = tid, idx1 = 256 + tid;
    int ar0 = bM * 128 + (idx0 >> 2); if (ar0 > M - 1) ar0 = M - 1;
    int ar1 = bM * 128 + (idx1 >> 2); if (ar1 > M - 1) ar1 = M - 1;
    const u16* Ab0 = A + (size_t)ar0 * K + (idx0 & 3) * 8;
    const u16* Ab1 = A + (size_t)ar1 * K + (idx1 & 3) * 8;
    const u16* Bb0 = Bt + (size_t)(bN * 128 + (idx0 >> 2)) * K + (idx0 & 3) * 8;
    const u16* Bb1 = Bt + (size_t)(bN * 128 + (idx1 >> 2)) * K + (idx1 & 3) * 8;

    for (int k0 = 0; k0 < K; k0 += 32) {
        __syncthreads();
        load_lds16(Ab0 + k0, &ldsA[idx0 * 8]);
        load_lds16(Ab1 + k0, &ldsA[idx1 * 8]);
        load_lds16(Bb0 + k0, &ldsB[idx0 * 8]);
        load_lds16(Bb1 + k0, &ldsB[idx1 * 8]);
        __syncthreads();

        s16x8 af[4], bfr[4];
#pragma unroll
        for (int rr = 0; rr < 4; rr++)
            af[rr] = *(const s16x8*)&ldsA[(wm * 64 + rr * 16 + lo) * 32 + qd * 8];
#pragma unroll
        for (int c = 0; c < 4; c++)
            bfr[c] = *(const s16x8*)&ldsB[(wn * 64 + c * 16 + lo) * 32 + qd * 8];
#pragma unroll
        for (int rr = 0; rr < 4; rr++)
#pragma unroll
            for (int c = 0; c < 4; c++)
                acc[rr][c] = __builtin_amdgcn_mfma_f32_16x16x32_bf16(af[rr], bfr[c], acc[rr][c], 0, 0, 0);
    }

    // C/D layout: col = lane&15, row = quad*4 + reg  [verified m89/m91]
#pragma unroll
    for (int rr = 0; rr < 4; rr++) {
        int row0 = bM * 128 + wm * 64 + rr * 16 + qd * 4;
#pragma unroll
        for (int c = 0; c < 4; c++) {
            int colI = bN * 128 + wn * 64 + c * 16 + lo;
            f32x4 a = acc[rr][c];
#pragma unroll
            for (int reg = 0; reg < 4; reg++) {
                int row = row0 + reg;
                if (row < M) C[(size_t)row * Nn + colI] = f2bf(a[reg]);
            }
        }
    }
}

// ---------- GCN aggregation: out[i] = relu(dis_i^2*h[i] + sum_e dis_i*dis_src*h[src] + b) ----------
__global__ __launch_bounds__(256) void k_agg(const u16* __restrict__ hin, u16* __restrict__ hout,
                                             const int* __restrict__ rowptr, const int* __restrict__ col,
                                             const float* __restrict__ dis, const float* __restrict__ bias) {
    int i = blockIdx.x;
    int t = threadIdx.x;  // 256 threads x 4 features
    float di = dis[i];
    int beg = rowptr[i], end = rowptr[i + 1];
    u16x4 v = *(const u16x4*)&hin[(size_t)i * H_DIM + t * 4];
    float w0 = di * di;
    float a0 = w0 * bf2f(v[0]), a1 = w0 * bf2f(v[1]);
    float a2 = w0 * bf2f(v[2]), a3 = w0 * bf2f(v[3]);
    for (int e = beg; e < end; ++e) {
        int s = col[e];                     // block-uniform
        float w = di * dis[s];
        u16x4 u = *(const u16x4*)&hin[(size_t)s * H_DIM + t * 4];
        a0 += w * bf2f(u[0]); a1 += w * bf2f(u[1]);
        a2 += w * bf2f(u[2]); a3 += w * bf2f(u[3]);
    }
    const float4 b = *(const float4*)&bias[t * 4];
    a0 = fmaxf(a0 + b.x, 0.f); a1 = fmaxf(a1 + b.y, 0.f);
    a2 = fmaxf(a2 + b.z, 0.f); a3 = fmaxf(a3 + b.w, 0.f);
    u16x4 o = { f2bf(a0), f2bf(a1), f2bf(a2), f2bf(a3) };
    *(u16x4*)&hout[(size_t)i * H_DIM + t * 4] = o;
}

// ---------- mean pool: chunked nodes, register segment-accumulate, atomic flush ----------
// grid: ceil(N/POOL_CHUNK) blocks x 256 threads (4 features each). batch sorted.
__global__ __launch_bounds__(256) void k_pool(const u16* __restrict__ h, const int* __restrict__ batch,
                                              float* __restrict__ pooled) {
    int t = threadIdx.x;
    int n0 = blockIdx.x * POOL_CHUNK;
    int n1 = min(n0 + POOL_CHUNK, N_NODES);
    float a0 = 0.f, a1 = 0.f, a2 = 0.f, a3 = 0.f;
    int curg = batch[n0];
    for (int n = n0; n < n1; ++n) {
        int g = batch[n];  // block-uniform
        if (g != curg) {   // uniform branch (rare: ~1-2 per block)
            float* p = &pooled[(size_t)curg * H_DIM + t * 4];
            atomicAdd(p + 0, a0); atomicAdd(p + 1, a1);
            atomicAdd(p + 2, a2); atomicAdd(p + 3, a3);
            a0 = a1 = a2 = a3 = 0.f;
            curg = g;
        }
        u16x4 v = *(const u16x4*)&h[(size_t)n * H_DIM + t * 4];
        a0 += bf2f(v[0]); a1 += bf2f(v[1]); a2 += bf2f(v[2]); a3 += bf2f(v[3]);
    }
    float* p = &pooled[(size_t)curg * H_DIM + t * 4];
    atomicAdd(p + 0, a0); atomicAdd(p + 1, a1);
    atomicAdd(p + 2, a2); atomicAdd(p + 3, a3);
}

// ---------- MLP head layer 1, split-K with atomic accumulation ----------
// grid: (16 gq, 4 jq, 8 kq); block 256. comb = [gx | pooled/count] per 4 graphs.
// hid accumulates raw (pre-bias, pre-relu); MLP2 applies bias+relu.
__global__ __launch_bounds__(256) void k_mlp1(const float* __restrict__ gx, const float* __restrict__ pooled,
                                              const int* __restrict__ cG,
                                              const float* __restrict__ fw1, float* __restrict__ hid) {
    __shared__ float comb[4 * MLP1_KC];
    int gq = blockIdx.x, jq = blockIdx.y, kq = blockIdx.z, t = threadIdx.x;
    int kbeg = kq * MLP1_KC;
    for (int idx = t; idx < 4 * MLP1_KC; idx += 256) {
        int gl = idx / MLP1_KC, kk = idx % MLP1_KC;
        int k = kbeg + kk;
        int g = gq * 4 + gl;
        float v;
        if (k < F_IN) v = gx[(size_t)g * F_IN + k];
        else v = pooled[(size_t)g * H_DIM + (k - F_IN)] / (float)max(cG[g], 1);
        comb[idx] = v;
    }
    __syncthreads();
    int j = jq * 256 + t;
    float a0 = 0, a1 = 0, a2 = 0, a3 = 0;
    for (int kk = 0; kk < MLP1_KC; ++kk) {
        float w = fw1[(size_t)(kbeg + kk) * FUSE_D + j];  // coalesced across lanes
        a0 += comb[kk] * w;
        a1 += comb[MLP1_KC + kk] * w;
        a2 += comb[2 * MLP1_KC + kk] * w;
        a3 += comb[3 * MLP1_KC + kk] * w;
    }
    atomicAdd(&hid[(size_t)(gq * 4 + 0) * FUSE_D + j], a0);
    atomicAdd(&hid[(size_t)(gq * 4 + 1) * FUSE_D + j], a1);
    atomicAdd(&hid[(size_t)(gq * 4 + 2) * FUSE_D + j], a2);
    atomicAdd(&hid[(size_t)(gq * 4 + 3) * FUSE_D + j], a3);
}

__global__ __launch_bounds__(128) void k_mlp2(const float* __restrict__ hid, const float* __restrict__ fb1,
                                              const float* __restrict__ fw2,
                                              const float* __restrict__ fb2, float* __restrict__ out) {
    __shared__ float hh[FUSE_D];
    int g = blockIdx.x, t = threadIdx.x;
    for (int idx = t; idx < FUSE_D; idx += 128)
        hh[idx] = fmaxf(hid[(size_t)g * FUSE_D + idx] + fb1[idx], 0.f);  // fused bias+relu
    __syncthreads();
    if (t < C_OUT) {
        float acc = fb2[t];
        for (int k = 0; k < FUSE_D; ++k) acc += hh[k] * fw2[k * C_OUT + t];
        out[g * C_OUT + t] = acc;
    }
}

extern "C" void kernel_launch(void* const* d_in, const int* in_sizes, int n_in,
                              void* d_out, int out_size, void* d_ws, size_t ws_size,
                              hipStream_t stream) {
    (void)in_sizes; (void)n_in; (void)out_size;
    const float* gx    = (const float*)d_in[0];
    const float* x     = (const float*)d_in[1];
    const int*   ei    = (const int*)d_in[2];
    const int*   batch = (const int*)d_in[3];
    const float* W1    = (const float*)d_in[4];
    const float* b1    = (const float*)d_in[5];
    const float* W2    = (const float*)d_in[6];
    const float* b2    = (const float*)d_in[7];
    const float* fw1   = (const float*)d_in[8];
    const float* fb1   = (const float*)d_in[9];
    const float* fw2   = (const float*)d_in[10];
    const float* fb2   = (const float*)d_in[11];
    float* out = (float*)d_out;
    const int* src = ei;
    const int* dst = ei + N_EDGES;

    // workspace layout (~366 MB total); zero zone at the end
    char* ws = (char*)d_ws;
    size_t off = 0;
    auto alloc = [&](size_t bytes) -> char* {
        char* p = ws + off;
        off += (bytes + 255) & ~(size_t)255;
        return p;
    };
    u16*  xb     = (u16*)alloc((size_t)N_NODES * F_IN * 2);   // reused as h2b
    u16*  h0b    = (u16*)alloc((size_t)N_NODES * H_DIM * 2);  // reused as h3b
    u16*  h1b    = (u16*)alloc((size_t)N_NODES * H_DIM * 2);
    u16*  W1T    = (u16*)alloc((size_t)H_DIM * F_IN * 2);
    u16*  W2T    = (u16*)alloc((size_t)H_DIM * H_DIM * 2);
    float* dis    = (float*)alloc((size_t)N_NODES * 4);
    int* rowptr   = (int*)alloc((size_t)(N_NODES + 1) * 4);
    int* col      = (int*)alloc((size_t)N_EDGES * 4);
    // ---- zero zone start ----
    int* cnt      = (int*)alloc((size_t)N_NODES * 4);
    int* cursor   = (int*)alloc((size_t)N_NODES * 4);
    int* cG       = (int*)alloc(256);
    float* pooled = (float*)alloc((size_t)N_GRAPH * H_DIM * 4);
    float* hid    = (float*)alloc((size_t)N_GRAPH * FUSE_D * 4);
    u16* h2b = xb;
    u16* h3b = h0b;
    (void)ws_size;

    // zero the accumulation zone (ws is poisoned 0xAA before every call)
    size_t zbytes = (size_t)((char*)(hid + N_GRAPH * FUSE_D) - (char*)cnt);
    hipMemsetAsync(cnt, 0, zbytes, stream);

    // graph prep
    k_deg<<<(N_EDGES + 255) / 256, 256, 0, stream>>>(dst, cnt);
    k_cg<<<(N_NODES + 255) / 256, 256, 0, stream>>>(batch, cG);
    k_scan<<<1, 1024, 0, stream>>>(cnt, rowptr, dis);
    k_fill<<<(N_EDGES + 255) / 256, 256, 0, stream>>>(src, dst, rowptr, cursor, col);

    // casts / weight transposes
    k_cvt<<<4096, 256, 0, stream>>>(x, xb, (long)N_NODES * F_IN);
    k_trn<<<dim3(H_DIM / 32, F_IN / 32), dim3(32, 8), 0, stream>>>(W1, W1T, F_IN, H_DIM);
    k_trn<<<dim3(H_DIM / 32, H_DIM / 32), dim3(32, 8), 0, stream>>>(W2, W2T, H_DIM, H_DIM);

    // GEMM grid: XCD-swizzled 1-D, 8 blocks per M-tile group, groups padded to x8
    const int MT = (N_NODES + 127) / 128;        // 391
    const int MTpad = ((MT + 7) / 8) * 8;        // 392
    const int GEMM_BLOCKS = 8 * MTpad;           // 3136

    // layer 1
    gemm_bt<<<GEMM_BLOCKS, 256, 0, stream>>>(xb, W1T, h0b, N_NODES, H_DIM, F_IN);
    k_agg<<<N_NODES, 256, 0, stream>>>(h0b, h1b, rowptr, col, dis, b1);
    // layer 2
    gemm_bt<<<GEMM_BLOCKS, 256, 0, stream>>>(h1b, W2T, h2b, N_NODES, H_DIM, H_DIM);
    k_agg<<<N_NODES, 256, 0, stream>>>(h2b, h3b, rowptr, col, dis, b2);

    // pool + head
    k_pool<<<(N_NODES + POOL_CHUNK - 1) / POOL_CHUNK, 256, 0, stream>>>(h3b, batch, pooled);
    k_mlp1<<<dim3(N_GRAPH / 4, FUSE_D / 256, 8), 256, 0, stream>>>(gx, pooled, cG, fw1, hid);
    k_mlp2<<<N_GRAPH, 128, 0, stream>>>(hid, fb1, fw2, fb2, out);
}

// Round 4
// 1599.449 us; speedup vs baseline: 1.1952x; 1.0151x over previous
//
#include <hip/hip_runtime.h>
#include <stdint.h>

// Problem constants (fixed-shape problem)
#define N_NODES 50000
#define N_EDGES 200000
#define N_GRAPH 64
#define F_IN    1536
#define H_DIM   1024
#define C_OUT   80
#define FUSE_D  1024
#define POOL_CHUNK 128
#define MLP1_KC 320   // 2560 / 8 k-chunks

typedef unsigned short u16;
typedef short s16x8 __attribute__((ext_vector_type(8)));
typedef float f32x4 __attribute__((ext_vector_type(4)));
typedef unsigned short u16x4 __attribute__((ext_vector_type(4)));
typedef unsigned short u16x8 __attribute__((ext_vector_type(8)));

// ---------- bf16 helpers (bit-level, RNE) ----------
__device__ __forceinline__ float bf2f(u16 u) {
    union { unsigned int i; float f; } v; v.i = ((unsigned int)u) << 16; return v.f;
}
__device__ __forceinline__ u16 f2bf(float f) {
    union { float f; unsigned int i; } v; v.f = f;
    unsigned int x = v.i;
    unsigned int r = (x + 0x7fffu + ((x >> 16) & 1u)) >> 16;
    return (u16)r;
}

// async global->LDS, 16 bytes per lane (lds dest must be linear in lane order)
__device__ __forceinline__ void load_lds16(const void* g, void* l) {
    __builtin_amdgcn_global_load_lds(
        (const __attribute__((address_space(1))) void*)g,
        (__attribute__((address_space(3))) void*)l, 16, 0, 0);
}

// ---------- graph prep kernels ----------
__global__ void k_deg(const int* __restrict__ dst, int* cnt) {
    int e = blockIdx.x * blockDim.x + threadIdx.x;
    if (e < N_EDGES) atomicAdd(&cnt[dst[e]], 1);
}

__global__ void k_cg(const int* __restrict__ batch, int* cG) {
    int i = blockIdx.x * blockDim.x + threadIdx.x;
    if (i < N_NODES) atomicAdd(&cG[batch[i]], 1);
}

// single-block exclusive scan of cnt -> rowptr, plus dis = rsqrt(deg+1)
__global__ __launch_bounds__(1024) void k_scan(const int* __restrict__ cnt,
                                               int* __restrict__ rowptr,
                                               float* __restrict__ dis) {
    __shared__ int lds[1024];
    int t = threadIdx.x;
    const int CH = (N_NODES + 1023) / 1024;  // 49
    int beg = t * CH, end = min(beg + CH, N_NODES);
    int s = 0;
    for (int i = beg; i < end; ++i) s += cnt[i];
    lds[t] = s;
    __syncthreads();
    for (int off = 1; off < 1024; off <<= 1) {
        int v = (t >= off) ? lds[t - off] : 0;
        __syncthreads();
        lds[t] += v;
        __syncthreads();
    }
    int run = lds[t] - s;  // exclusive prefix
    for (int i = beg; i < end; ++i) {
        rowptr[i] = run;
        int c = cnt[i];
        run += c;
        dis[i] = rsqrtf((float)(c + 1));  // +1 self-loop; deg>=1 always
    }
    if (t == 1023) rowptr[N_NODES] = lds[1023];
}

__global__ void k_fill(const int* __restrict__ src, const int* __restrict__ dst,
                       const int* __restrict__ rowptr, int* cursor, int* col) {
    int e = blockIdx.x * blockDim.x + threadIdx.x;
    if (e < N_EDGES) {
        int d = dst[e];
        int p = atomicAdd(&cursor[d], 1);
        col[rowptr[d] + p] = src[e];
    }
}

// ---------- fp32 -> bf16 cast (vectorized) ----------
__global__ void k_cvt(const float* __restrict__ in, u16* __restrict__ out, long n) {
    long i = (long)blockIdx.x * blockDim.x + threadIdx.x;
    long stride = (long)gridDim.x * blockDim.x;
    for (long v = i * 4; v < n; v += stride * 4) {
        float4 f = *(const float4*)(in + v);
        u16x4 o = { f2bf(f.x), f2bf(f.y), f2bf(f.z), f2bf(f.w) };
        *(u16x4*)(out + v) = o;
    }
}

// W [K x Nn] fp32 -> Wt [Nn x K] bf16 (tiled transpose)
__global__ void k_trn(const float* __restrict__ W, u16* __restrict__ Wt, int K, int Nn) {
    __shared__ float tle[32][33];
    int n0 = blockIdx.x * 32, k0 = blockIdx.y * 32;
    int tx = threadIdx.x, ty = threadIdx.y;  // 32 x 8
    for (int i = ty; i < 32; i += 8)
        tle[i][tx] = W[(size_t)(k0 + i) * Nn + n0 + tx];
    __syncthreads();
    for (int i = ty; i < 32; i += 8)
        Wt[(size_t)(n0 + i) * K + k0 + tx] = f2bf(tle[tx][i]);
}

// ---------- MFMA GEMM: C[MxNn] = A[MxK] @ Bt[NnxK]^T, all bf16, C bf16 ----------
// 128x128 block tile, BK=32, 4 waves each 64x64 (4x4 of 16x16x32 MFMA).
// XCD-aware swizzle: all 8 N-tiles of one M-tile group -> same XCD (l%8 rr).
// LDS bank-conflict fix: chunk (row, kc) stored at slot (row, kc ^ ((row>>1)&3)).
// Staging stays lane-linear (global_load_lds constraint); the READ side address
// permutes, spreading 16 lanes over all 8 bank-spans (2-way = free, m136).
__global__ __launch_bounds__(256) void gemm_bt(const u16* __restrict__ A,
                                               const u16* __restrict__ Bt,
                                               u16* __restrict__ C,
                                               int M, int Nn, int K) {
    __shared__ __attribute__((aligned(16))) u16 ldsA[128 * 32];
    __shared__ __attribute__((aligned(16))) u16 ldsB[128 * 32];
    int l = blockIdx.x;
    int r = l & 7;             // XCD id (round-robin l%8)
    int o = l >> 3;            // per-XCD ordinal
    int bN = o & 7;            // 8 N-tiles (Nn=1024)
    int bM = r + ((o >> 3) << 3);
    int MT = (M + 127) >> 7;
    if (bM >= MT) return;

    int tid = threadIdx.x;
    int lane = tid & 63, wave = tid >> 6;
    int wm = wave & 1, wn = wave >> 1;
    int qd = lane >> 4, lo = lane & 15;

    f32x4 acc[4][4] = {};

    // staging: 512 chunks of 16B per tile (2 per thread), lds slot = idx (linear),
    // source k-chunk = (idx&3) ^ ((row>>1)&3)   [bank-conflict swizzle]
    int idx0 = tid, idx1 = 256 + tid;
    int row0i = idx0 >> 2, row1i = idx1 >> 2;
    int kc0 = (idx0 & 3) ^ ((row0i >> 1) & 3);
    int kc1 = (idx1 & 3) ^ ((row1i >> 1) & 3);
    int ar0 = bM * 128 + row0i; if (ar0 > M - 1) ar0 = M - 1;
    int ar1 = bM * 128 + row1i; if (ar1 > M - 1) ar1 = M - 1;
    const u16* Ab0 = A + (size_t)ar0 * K + kc0 * 8;
    const u16* Ab1 = A + (size_t)ar1 * K + kc1 * 8;
    const u16* Bb0 = Bt + (size_t)(bN * 128 + row0i) * K + kc0 * 8;
    const u16* Bb1 = Bt + (size_t)(bN * 128 + row1i) * K + kc1 * 8;

    for (int k0 = 0; k0 < K; k0 += 32) {
        __syncthreads();
        load_lds16(Ab0 + k0, &ldsA[idx0 * 8]);
        load_lds16(Ab1 + k0, &ldsA[idx1 * 8]);
        load_lds16(Bb0 + k0, &ldsB[idx0 * 8]);
        load_lds16(Bb1 + k0, &ldsB[idx1 * 8]);
        __syncthreads();

        s16x8 af[4], bfr[4];
#pragma unroll
        for (int rr = 0; rr < 4; rr++) {
            int row = wm * 64 + rr * 16 + lo;
            int slot = row * 4 + (qd ^ ((row >> 1) & 3));
            af[rr] = *(const s16x8*)&ldsA[slot * 8];
        }
#pragma unroll
        for (int c = 0; c < 4; c++) {
            int row = wn * 64 + c * 16 + lo;
            int slot = row * 4 + (qd ^ ((row >> 1) & 3));
            bfr[c] = *(const s16x8*)&ldsB[slot * 8];
        }
#pragma unroll
        for (int rr = 0; rr < 4; rr++)
#pragma unroll
            for (int c = 0; c < 4; c++)
                acc[rr][c] = __builtin_amdgcn_mfma_f32_16x16x32_bf16(af[rr], bfr[c], acc[rr][c], 0, 0, 0);
    }

    // C/D layout: col = lane&15, row = quad*4 + reg  [verified m89/m91]
#pragma unroll
    for (int rr = 0; rr < 4; rr++) {
        int rowb = bM * 128 + wm * 64 + rr * 16 + qd * 4;
#pragma unroll
        for (int c = 0; c < 4; c++) {
            int colI = bN * 128 + wn * 64 + c * 16 + lo;
            f32x4 a = acc[rr][c];
#pragma unroll
            for (int reg = 0; reg < 4; reg++) {
                int row = rowb + reg;
                if (row < M) C[(size_t)row * Nn + colI] = f2bf(a[reg]);
            }
        }
    }
}

// ---------- GCN aggregation, wave-per-node: 4 nodes/block, 64 lanes x 16 feats ----
// out[i] = relu(dis_i^2*h[i] + sum_e dis_i*dis_src*h[src] + b)
__global__ __launch_bounds__(256) void k_agg(const u16* __restrict__ hin, u16* __restrict__ hout,
                                             const int* __restrict__ rowptr, const int* __restrict__ col,
                                             const float* __restrict__ dis, const float* __restrict__ bias) {
    int w = threadIdx.x >> 6, lane = threadIdx.x & 63;
    int i = blockIdx.x * 4 + w;            // N_NODES % 4 == 0
    float di = dis[i];
    int beg = rowptr[i], end = rowptr[i + 1];
    const u16* hrow = hin + (size_t)i * H_DIM + lane * 16;
    u16x8 v0 = *(const u16x8*)hrow;
    u16x8 v1 = *(const u16x8*)(hrow + 8);
    float w0 = di * di;
    float acc[16];
#pragma unroll
    for (int j = 0; j < 8; j++) { acc[j] = w0 * bf2f(v0[j]); acc[8 + j] = w0 * bf2f(v1[j]); }
    for (int e = beg; e < end; ++e) {
        int s = col[e];                     // wave-uniform
        float wgt = di * dis[s];
        const u16* nrow = hin + (size_t)s * H_DIM + lane * 16;
        u16x8 u0 = *(const u16x8*)nrow;
        u16x8 u1 = *(const u16x8*)(nrow + 8);
#pragma unroll
        for (int j = 0; j < 8; j++) { acc[j] += wgt * bf2f(u0[j]); acc[8 + j] += wgt * bf2f(u1[j]); }
    }
    const float* bp = bias + lane * 16;
    u16x8 o0, o1;
#pragma unroll
    for (int j = 0; j < 8; j++) {
        o0[j] = f2bf(fmaxf(acc[j] + bp[j], 0.f));
        o1[j] = f2bf(fmaxf(acc[8 + j] + bp[8 + j], 0.f));
    }
    u16* orow = hout + (size_t)i * H_DIM + lane * 16;
    *(u16x8*)orow = o0;
    *(u16x8*)(orow + 8) = o1;
}

// ---------- mean pool: chunked nodes, register segment-accumulate, atomic flush ----------
// grid: ceil(N/POOL_CHUNK) blocks x 256 threads (4 features each). batch sorted.
__global__ __launch_bounds__(256) void k_pool(const u16* __restrict__ h, const int* __restrict__ batch,
                                              float* __restrict__ pooled) {
    int t = threadIdx.x;
    int n0 = blockIdx.x * POOL_CHUNK;
    int n1 = min(n0 + POOL_CHUNK, N_NODES);
    float a0 = 0.f, a1 = 0.f, a2 = 0.f, a3 = 0.f;
    int curg = batch[n0];
    for (int n = n0; n < n1; ++n) {
        int g = batch[n];  // block-uniform
        if (g != curg) {   // uniform branch (rare: ~1-2 per block)
            float* p = &pooled[(size_t)curg * H_DIM + t * 4];
            atomicAdd(p + 0, a0); atomicAdd(p + 1, a1);
            atomicAdd(p + 2, a2); atomicAdd(p + 3, a3);
            a0 = a1 = a2 = a3 = 0.f;
            curg = g;
        }
        u16x4 v = *(const u16x4*)&h[(size_t)n * H_DIM + t * 4];
        a0 += bf2f(v[0]); a1 += bf2f(v[1]); a2 += bf2f(v[2]); a3 += bf2f(v[3]);
    }
    float* p = &pooled[(size_t)curg * H_DIM + t * 4];
    atomicAdd(p + 0, a0); atomicAdd(p + 1, a1);
    atomicAdd(p + 2, a2); atomicAdd(p + 3, a3);
}

// ---------- MLP head layer 1, split-K with atomic accumulation ----------
// grid: (16 gq, 4 jq, 8 kq); block 256. comb = [gx | pooled/count] per 4 graphs.
// hid accumulates raw (pre-bias, pre-relu); MLP2 applies bias+relu.
__global__ __launch_bounds__(256) void k_mlp1(const float* __restrict__ gx, const float* __restrict__ pooled,
                                              const int* __restrict__ cG,
                                              const float* __restrict__ fw1, float* __restrict__ hid) {
    __shared__ float comb[4 * MLP1_KC];
    int gq = blockIdx.x, jq = blockIdx.y, kq = blockIdx.z, t = threadIdx.x;
    int kbeg = kq * MLP1_KC;
    for (int idx = t; idx < 4 * MLP1_KC; idx += 256) {
        int gl = idx / MLP1_KC, kk = idx % MLP1_KC;
        int k = kbeg + kk;
        int g = gq * 4 + gl;
        float v;
        if (k < F_IN) v = gx[(size_t)g * F_IN + k];
        else v = pooled[(size_t)g * H_DIM + (k - F_IN)] / (float)max(cG[g], 1);
        comb[idx] = v;
    }
    __syncthreads();
    int j = jq * 256 + t;
    float a0 = 0, a1 = 0, a2 = 0, a3 = 0;
    for (int kk = 0; kk < MLP1_KC; ++kk) {
        float w = fw1[(size_t)(kbeg + kk) * FUSE_D + j];  // coalesced across lanes
        a0 += comb[kk] * w;
        a1 += comb[MLP1_KC + kk] * w;
        a2 += comb[2 * MLP1_KC + kk] * w;
        a3 += comb[3 * MLP1_KC + kk] * w;
    }
    atomicAdd(&hid[(size_t)(gq * 4 + 0) * FUSE_D + j], a0);
    atomicAdd(&hid[(size_t)(gq * 4 + 1) * FUSE_D + j], a1);
    atomicAdd(&hid[(size_t)(gq * 4 + 2) * FUSE_D + j], a2);
    atomicAdd(&hid[(size_t)(gq * 4 + 3) * FUSE_D + j], a3);
}

__global__ __launch_bounds__(128) void k_mlp2(const float* __restrict__ hid, const float* __restrict__ fb1,
                                              const float* __restrict__ fw2,
                                              const float* __restrict__ fb2, float* __restrict__ out) {
    __shared__ float hh[FUSE_D];
    int g = blockIdx.x, t = threadIdx.x;
    for (int idx = t; idx < FUSE_D; idx += 128)
        hh[idx] = fmaxf(hid[(size_t)g * FUSE_D + idx] + fb1[idx], 0.f);  // fused bias+relu
    __syncthreads();
    if (t < C_OUT) {
        float acc = fb2[t];
        for (int k = 0; k < FUSE_D; ++k) acc += hh[k] * fw2[k * C_OUT + t];
        out[g * C_OUT + t] = acc;
    }
}

extern "C" void kernel_launch(void* const* d_in, const int* in_sizes, int n_in,
                              void* d_out, int out_size, void* d_ws, size_t ws_size,
                              hipStream_t stream) {
    (void)in_sizes; (void)n_in; (void)out_size;
    const float* gx    = (const float*)d_in[0];
    const float* x     = (const float*)d_in[1];
    const int*   ei    = (const int*)d_in[2];
    const int*   batch = (const int*)d_in[3];
    const float* W1    = (const float*)d_in[4];
    const float* b1    = (const float*)d_in[5];
    const float* W2    = (const float*)d_in[6];
    const float* b2    = (const float*)d_in[7];
    const float* fw1   = (const float*)d_in[8];
    const float* fb1   = (const float*)d_in[9];
    const float* fw2   = (const float*)d_in[10];
    const float* fb2   = (const float*)d_in[11];
    float* out = (float*)d_out;
    const int* src = ei;
    const int* dst = ei + N_EDGES;

    // workspace layout (~366 MB total); zero zone at the end
    char* ws = (char*)d_ws;
    size_t off = 0;
    auto alloc = [&](size_t bytes) -> char* {
        char* p = ws + off;
        off += (bytes + 255) & ~(size_t)255;
        return p;
    };
    u16*  xb     = (u16*)alloc((size_t)N_NODES * F_IN * 2);   // reused as h2b
    u16*  h0b    = (u16*)alloc((size_t)N_NODES * H_DIM * 2);  // reused as h3b
    u16*  h1b    = (u16*)alloc((size_t)N_NODES * H_DIM * 2);
    u16*  W1T    = (u16*)alloc((size_t)H_DIM * F_IN * 2);
    u16*  W2T    = (u16*)alloc((size_t)H_DIM * H_DIM * 2);
    float* dis    = (float*)alloc((size_t)N_NODES * 4);
    int* rowptr   = (int*)alloc((size_t)(N_NODES + 1) * 4);
    int* col      = (int*)alloc((size_t)N_EDGES * 4);
    // ---- zero zone start ----
    int* cnt      = (int*)alloc((size_t)N_NODES * 4);
    int* cursor   = (int*)alloc((size_t)N_NODES * 4);
    int* cG       = (int*)alloc(256);
    float* pooled = (float*)alloc((size_t)N_GRAPH * H_DIM * 4);
    float* hid    = (float*)alloc((size_t)N_GRAPH * FUSE_D * 4);
    u16* h2b = xb;
    u16* h3b = h0b;
    (void)ws_size;

    // zero the accumulation zone (ws is poisoned 0xAA before every call)
    size_t zbytes = (size_t)((char*)(hid + N_GRAPH * FUSE_D) - (char*)cnt);
    hipMemsetAsync(cnt, 0, zbytes, stream);

    // graph prep
    k_deg<<<(N_EDGES + 255) / 256, 256, 0, stream>>>(dst, cnt);
    k_cg<<<(N_NODES + 255) / 256, 256, 0, stream>>>(batch, cG);
    k_scan<<<1, 1024, 0, stream>>>(cnt, rowptr, dis);
    k_fill<<<(N_EDGES + 255) / 256, 256, 0, stream>>>(src, dst, rowptr, cursor, col);

    // casts / weight transposes
    k_cvt<<<4096, 256, 0, stream>>>(x, xb, (long)N_NODES * F_IN);
    k_trn<<<dim3(H_DIM / 32, F_IN / 32), dim3(32, 8), 0, stream>>>(W1, W1T, F_IN, H_DIM);
    k_trn<<<dim3(H_DIM / 32, H_DIM / 32), dim3(32, 8), 0, stream>>>(W2, W2T, H_DIM, H_DIM);

    // GEMM grid: XCD-swizzled 1-D, 8 blocks per M-tile group, groups padded to x8
    const int MT = (N_NODES + 127) / 128;        // 391
    const int MTpad = ((MT + 7) / 8) * 8;        // 392
    const int GEMM_BLOCKS = 8 * MTpad;           // 3136

    // layer 1
    gemm_bt<<<GEMM_BLOCKS, 256, 0, stream>>>(xb, W1T, h0b, N_NODES, H_DIM, F_IN);
    k_agg<<<N_NODES / 4, 256, 0, stream>>>(h0b, h1b, rowptr, col, dis, b1);
    // layer 2
    gemm_bt<<<GEMM_BLOCKS, 256, 0, stream>>>(h1b, W2T, h2b, N_NODES, H_DIM, H_DIM);
    k_agg<<<N_NODES / 4, 256, 0, stream>>>(h2b, h3b, rowptr, col, dis, b2);

    // pool + head
    k_pool<<<(N_NODES + POOL_CHUNK - 1) / POOL_CHUNK, 256, 0, stream>>>(h3b, batch, pooled);
    k_mlp1<<<dim3(N_GRAPH / 4, FUSE_D / 256, 8), 256, 0, stream>>>(gx, pooled, cG, fw1, hid);
    k_mlp2<<<N_GRAPH, 128, 0, stream>>>(hid, fb1, fw2, fb2, out);
}